// Round 1
// baseline (261.827 us; speedup 1.0000x reference)
//
#include <hip/hip_runtime.h>

typedef __attribute__((ext_vector_type(8))) short short8;
typedef __attribute__((ext_vector_type(4))) float f32x4;
typedef __attribute__((ext_vector_type(4))) unsigned int u32x4;
typedef __attribute__((ext_vector_type(2))) unsigned int u32x2;

#define MFMA16(A, B, C) __builtin_amdgcn_mfma_f32_16x16x32_bf16((A), (B), (C), 0, 0, 0)

__device__ __forceinline__ unsigned int fbits(float f) {
  return __builtin_bit_cast(unsigned int, f);
}
// pack two floats -> two bf16 (truncate): low ushort = a, high = b
__device__ __forceinline__ unsigned int pack_bf16(float a, float b) {
  return __builtin_amdgcn_perm(fbits(b), fbits(a), 0x07060302u);
}
__device__ __forceinline__ unsigned short bf16_rne(float f) {
  unsigned int u = fbits(f);
  return (unsigned short)((u + 0x8000u) >> 16);
}

// ---------------------------------------------------------------------------
// Kernel 1: W (256x256 fp32) -> WT (bf16, [n][k]) for all three weights.
// ---------------------------------------------------------------------------
__global__ __launch_bounds__(256) void wtrans_kernel(
    const float* __restrict__ Wq, const float* __restrict__ Wk,
    const float* __restrict__ Wv, unsigned short* __restrict__ WT) {
  __shared__ float tile[32][33];
  const int bid = blockIdx.x;
  const int g = bid / 64, rem = bid % 64;
  const int k0 = (rem >> 3) * 32, n0 = (rem & 7) * 32;
  const float* W = (g == 0) ? Wq : (g == 1) ? Wk : Wv;
  const int t = threadIdx.x;
  {
    const int kr = t >> 3, nc = (t & 7) * 4;
    const float4 f = *(const float4*)(W + (size_t)(k0 + kr) * 256 + n0 + nc);
    tile[kr][nc + 0] = f.x; tile[kr][nc + 1] = f.y;
    tile[kr][nc + 2] = f.z; tile[kr][nc + 3] = f.w;
  }
  __syncthreads();
  {
    const int nr = t >> 3, kc = (t & 7) * 4;
    unsigned int u0 = (unsigned int)bf16_rne(tile[kc + 0][nr]) |
                      ((unsigned int)bf16_rne(tile[kc + 1][nr]) << 16);
    unsigned int u1 = (unsigned int)bf16_rne(tile[kc + 2][nr]) |
                      ((unsigned int)bf16_rne(tile[kc + 3][nr]) << 16);
    u32x2 u = {u0, u1};
    *(u32x2*)(WT + (size_t)g * 65536 + (size_t)(n0 + nr) * 256 + k0 + kc) = u;
  }
}

// ---------------------------------------------------------------------------
// Kernel 2: fused QKV projection GEMM. x[16384,256] fp32 @ W[256,256] -> bf16.
// Q gets the 1/sqrt(dk) scale folded in. V is written transposed per head:
// VT[(b*8+h)*32 + d][n].
// Tile: 128(M) x 64(N), K=256, 4 waves, wave = 2 strips of 16 rows x 64 cols.
// ---------------------------------------------------------------------------
__global__ __launch_bounds__(256) void proj_kernel(
    const float* __restrict__ x, const unsigned short* __restrict__ WT,
    unsigned short* __restrict__ Q, unsigned short* __restrict__ K,
    unsigned short* __restrict__ VT) {
  const int tid = threadIdx.x;
  const int w = tid >> 6, lane = tid & 63, l15 = lane & 15, quad = lane >> 4;
  const int bid = blockIdx.x;
  const int mtile = bid / 12, nt = bid % 12;
  const int g = nt >> 2, n0 = (nt & 3) * 64;
  const int m0 = mtile * 128 + w * 32;
  const float* xp = x + (size_t)(m0 + l15) * 256 + quad * 8;
  const unsigned short* wp =
      WT + (size_t)g * 65536 + (size_t)(n0 + l15) * 256 + quad * 8;
  const f32x4 zero = {0.f, 0.f, 0.f, 0.f};
  f32x4 acc[2][4];
#pragma unroll
  for (int s = 0; s < 2; s++)
#pragma unroll
    for (int c = 0; c < 4; c++) acc[s][c] = zero;

  for (int k0 = 0; k0 < 256; k0 += 32) {
    short8 a[2];
#pragma unroll
    for (int s = 0; s < 2; s++) {
      const float* p = xp + (size_t)s * 4096 + k0;  // s*16 rows * 256
      float4 f0 = *(const float4*)p;
      float4 f1 = *(const float4*)(p + 4);
      u32x4 u = {pack_bf16(f0.x, f0.y), pack_bf16(f0.z, f0.w),
                 pack_bf16(f1.x, f1.y), pack_bf16(f1.z, f1.w)};
      a[s] = __builtin_bit_cast(short8, u);
    }
    short8 bfrag[4];
#pragma unroll
    for (int c = 0; c < 4; c++)
      bfrag[c] = *(const short8*)(wp + (size_t)c * 4096 + k0);  // c*16 rows
#pragma unroll
    for (int s = 0; s < 2; s++)
#pragma unroll
      for (int c = 0; c < 4; c++)
        acc[s][c] = MFMA16(a[s], bfrag[c], acc[s][c]);
  }

  if (g < 2) {
    unsigned short* O = g ? K : Q;
    const float scale = g ? 1.0f : 0.17677669529663688f;  // 1/sqrt(32) into Q
#pragma unroll
    for (int s = 0; s < 2; s++)
#pragma unroll
      for (int c = 0; c < 4; c++)
#pragma unroll
        for (int r = 0; r < 4; r++) {
          const int row = m0 + s * 16 + quad * 4 + r;
          const int col = n0 + c * 16 + l15;
          O[(size_t)row * 256 + col] = bf16_rne(acc[s][c][r] * scale);
        }
  } else {
    // V: C/D rows (quad*4+r) are consecutive sequence positions -> contiguous
    // in VT; pack 4 bf16 and store 8B.
#pragma unroll
    for (int s = 0; s < 2; s++)
#pragma unroll
      for (int c = 0; c < 4; c++) {
        const int col = n0 + c * 16 + l15;  // 0..255 = h*32 + d
        const int hh = col >> 5, dloc = col & 31;
        const int row = m0 + s * 16 + quad * 4;
        const int bb = row >> 12, nn = row & 4095;
        u32x2 pk = {pack_bf16(acc[s][c][0], acc[s][c][1]),
                    pack_bf16(acc[s][c][2], acc[s][c][3])};
        *(u32x2*)(VT + (size_t)((bb * 8 + hh) * 32 + dloc) * 4096 + nn) = pk;
      }
  }
}

// ---------------------------------------------------------------------------
// Kernel 3: attention. Per block: one (b,h), 256 q-rows. Per wave: 64 q-rows
// (4 strips of 16). K-tile = 64 keys/iter.
// S^T = K·Q^T trick: C/D gives each lane 4 consecutive keys at fixed q ->
// packed b64 LDS writes of leaky(S); read back 16B-contiguous as PV A-operand.
// P is per-wave-private LDS -> no __syncthreads, DS in-order per wave.
// ---------------------------------------------------------------------------
__global__ __launch_bounds__(256) void attn_kernel(
    const unsigned short* __restrict__ Q, const unsigned short* __restrict__ K,
    const unsigned short* __restrict__ VT, float* __restrict__ out) {
  __shared__ __align__(16) unsigned short P[16][16][72];  // [w*4+s][q][key+pad]
  const int tid = threadIdx.x;
  const int w = tid >> 6, lane = tid & 63, l15 = lane & 15, quad = lane >> 4;
  const int bid = blockIdx.x;
  const int bh = bid >> 4, qt = bid & 15;
  const int b = bh >> 3, h = bh & 7;
  const int qbase = qt * 256 + w * 64;

  const unsigned short* Qp =
      Q + (size_t)(b * 4096 + qbase + l15) * 256 + h * 32 + quad * 8;
  short8 qf[4];
#pragma unroll
  for (int s = 0; s < 4; s++) qf[s] = *(const short8*)(Qp + (size_t)s * 4096);

  const unsigned short* Kp =
      K + (size_t)(b * 4096 + l15) * 256 + h * 32 + quad * 8;
  const unsigned short* Vp = VT + (size_t)(bh * 32 + l15) * 4096 + quad * 8;

  const f32x4 zero = {0.f, 0.f, 0.f, 0.f};
  f32x4 acc[4][2];
#pragma unroll
  for (int s = 0; s < 4; s++) {
    acc[s][0] = zero;
    acc[s][1] = zero;
  }

  for (int kb = 0; kb < 4096; kb += 64) {
    short8 kf[4];
#pragma unroll
    for (int c = 0; c < 4; c++)
      kf[c] = *(const short8*)(Kp + (size_t)(kb + c * 16) * 256);

    // S^T tiles: A = K (m=key), B = Q^T (n=q). D row=key=quad*4+r, col=q=l15.
#pragma unroll
    for (int s = 0; s < 4; s++) {
#pragma unroll
      for (int c = 0; c < 4; c++) {
        f32x4 st = MFMA16(kf[c], qf[s], zero);
        float t0 = fmaxf(st[0], 0.2f * st[0]);  // Q pre-scaled by 1/sqrt(dk)
        float t1 = fmaxf(st[1], 0.2f * st[1]);
        float t2 = fmaxf(st[2], 0.2f * st[2]);
        float t3 = fmaxf(st[3], 0.2f * st[3]);
        u32x2 pk = {pack_bf16(t0, t1), pack_bf16(t2, t3)};
        *(u32x2*)(&P[w * 4 + s][l15][c * 16 + quad * 4]) = pk;
      }
    }
    __builtin_amdgcn_wave_barrier();  // order P writes before P reads (same wave)

    // PV: A = P (m=q, k=key), B = V (k=key, n=d) from VT.
#pragma unroll
    for (int hk = 0; hk < 2; hk++) {
      short8 vf[2];
#pragma unroll
      for (int dh = 0; dh < 2; dh++)
        vf[dh] = *(const short8*)(Vp + (size_t)(dh * 16) * 4096 + kb + hk * 32);
#pragma unroll
      for (int s = 0; s < 4; s++) {
        short8 pa = *(const short8*)(&P[w * 4 + s][l15][hk * 32 + quad * 8]);
#pragma unroll
        for (int dh = 0; dh < 2; dh++)
          acc[s][dh] = MFMA16(pa, vf[dh], acc[s][dh]);
      }
    }
    __builtin_amdgcn_wave_barrier();  // WAR: reads done before next overwrite
  }

  // Epilogue: D row=q=quad*4+r, col=d=l15. Output [b][n][h*32+d] fp32.
#pragma unroll
  for (int s = 0; s < 4; s++)
#pragma unroll
    for (int dh = 0; dh < 2; dh++)
#pragma unroll
      for (int r = 0; r < 4; r++)
        out[(size_t)(b * 4096 + qbase + s * 16 + quad * 4 + r) * 256 + h * 32 +
            dh * 16 + l15] = acc[s][dh][r];
}

// ---------------------------------------------------------------------------
extern "C" void kernel_launch(void* const* d_in, const int* in_sizes, int n_in,
                              void* d_out, int out_size, void* d_ws,
                              size_t ws_size, hipStream_t stream) {
  const float* x = (const float*)d_in[0];
  const float* Wq = (const float*)d_in[1];
  const float* Wk = (const float*)d_in[2];
  const float* Wv = (const float*)d_in[3];
  float* out = (float*)d_out;

  // Workspace (bf16): Q | K | VT | WT   (25.6 MB total)
  unsigned short* ws = (unsigned short*)d_ws;
  unsigned short* Qb = ws;                    // 16384*256
  unsigned short* Kb = ws + 4194304;          // 16384*256
  unsigned short* VTb = ws + 2 * 4194304;     // 32 heads * 32 d * 4096 n
  unsigned short* WTb = ws + 3 * 4194304;     // 3 * 256 * 256

  wtrans_kernel<<<192, 256, 0, stream>>>(Wq, Wk, Wv, WTb);
  proj_kernel<<<1536, 256, 0, stream>>>(x, WTb, Qb, Kb, VTb);
  attn_kernel<<<512, 256, 0, stream>>>(Qb, Kb, VTb, out);
}